// Round 15
// baseline (293.017 us; speedup 1.0000x reference)
//
#include <hip/hip_runtime.h>
#include <hip/hip_fp16.h>
#include <stdint.h>

typedef _Float16 f16x8 __attribute__((ext_vector_type(8)));
typedef float f32x4 __attribute__((ext_vector_type(4)));

// ---------------------------------------------------------------- CSR build
// edge_index arrives as int32 (harness converts integer inputs to int32).
// R4: deterministic two-level bucket CSR build (no global-atomic scatter).
// R13: R11's measured-best config (CH=2048, shift=7 -> 782 blocks).

#define CH 2048           // edges per block in bucket passes
#define MAXNB 1024        // max bucket count supported by LDS arrays

__global__ __launch_bounds__(256) void bhist_k(const int* __restrict__ ei,
        int* __restrict__ bh, int E, int shift, int NB, int NBLK) {
    __shared__ int lh[MAXNB];
    for (int b = threadIdx.x; b < NB; b += 256) lh[b] = 0;
    __syncthreads();
    int base = blockIdx.x * CH;
    int end = min(base + CH, E);
    for (int e = base + threadIdx.x; e < end; e += 256) {
        int t = ei[(size_t)E + e];
        atomicAdd(&lh[t >> shift], 1);
    }
    __syncthreads();
    for (int b = threadIdx.x; b < NB; b += 256)
        bh[(size_t)b * NBLK + blockIdx.x] = lh[b];   // column-major per bucket
}

// Exclusive scan of each bucket's per-block counts (NBLK <= 1024).
__global__ __launch_bounds__(256) void scan_col_k(int* bh, int* __restrict__ btot,
                                                  int NBLK, int NB) {
    __shared__ int sd[256];
    size_t rowoff = (size_t)blockIdx.x * NBLK;
    int t = threadIdx.x;
    int base = t * 4;
    int v0 = (base + 0 < NBLK) ? bh[rowoff + base + 0] : 0;
    int v1 = (base + 1 < NBLK) ? bh[rowoff + base + 1] : 0;
    int v2 = (base + 2 < NBLK) ? bh[rowoff + base + 2] : 0;
    int v3 = (base + 3 < NBLK) ? bh[rowoff + base + 3] : 0;
    int s = v0 + v1 + v2 + v3;
    sd[t] = s;
    __syncthreads();
    for (int off = 1; off < 256; off <<= 1) {
        int x = (t >= off) ? sd[t - off] : 0;
        __syncthreads();
        sd[t] += x;
        __syncthreads();
    }
    int ex = sd[t] - s;
    if (base + 0 < NBLK) bh[rowoff + base + 0] = ex;
    if (base + 1 < NBLK) bh[rowoff + base + 1] = ex + v0;
    if (base + 2 < NBLK) bh[rowoff + base + 2] = ex + v0 + v1;
    if (base + 3 < NBLK) bh[rowoff + base + 3] = ex + v0 + v1 + v2;
    if (t == 255) btot[blockIdx.x] = sd[255];
}

__global__ void scan_block_k(const int* __restrict__ deg, int* __restrict__ excl,
                             int* __restrict__ bsum, int N) {
    __shared__ int sd[256];
    int t = threadIdx.x;
    int base = blockIdx.x * 1024 + t * 4;
    int v0 = (base + 0 < N) ? deg[base + 0] : 0;
    int v1 = (base + 1 < N) ? deg[base + 1] : 0;
    int v2 = (base + 2 < N) ? deg[base + 2] : 0;
    int v3 = (base + 3 < N) ? deg[base + 3] : 0;
    int s = v0 + v1 + v2 + v3;
    sd[t] = s;
    __syncthreads();
    for (int off = 1; off < 256; off <<= 1) {
        int x = (t >= off) ? sd[t - off] : 0;
        __syncthreads();
        sd[t] += x;
        __syncthreads();
    }
    int incl = sd[t];
    int ex = incl - s;
    if (base + 0 < N) excl[base + 0] = ex;
    if (base + 1 < N) excl[base + 1] = ex + v0;
    if (base + 2 < N) excl[base + 2] = ex + v0 + v1;
    if (base + 3 < N) excl[base + 3] = ex + v0 + v1 + v2;
    if (t == 255) bsum[blockIdx.x] = incl;
}

__global__ __launch_bounds__(256) void bscatter_k(const int* __restrict__ ei,
        const int* __restrict__ bh, const int* __restrict__ bbase,
        int* __restrict__ staged, int E, int shift, int NB, int NBLK) {
    __shared__ int cur[MAXNB];
    for (int b = threadIdx.x; b < NB; b += 256)
        cur[b] = bbase[b] + bh[(size_t)b * NBLK + blockIdx.x];
    __syncthreads();
    int base = blockIdx.x * CH;
    int end = min(base + CH, E);
    int mask = (1 << shift) - 1;
    for (int e = base + threadIdx.x; e < end; e += 256) {
        int s = ei[e];
        int t = ei[(size_t)E + e];
        int p = atomicAdd(&cur[t >> shift], 1);
        staged[p] = s | ((t & mask) << 17);
    }
}

__global__ __launch_bounds__(256) void csrfill_k(const int* __restrict__ staged,
        const int* __restrict__ bbase, int* __restrict__ rs, int* __restrict__ csr,
        int N, int E, int shift, int NB) {
    __shared__ int lh[256];
    __shared__ int sd[256];
    int b = blockIdx.x;
    int tpb = 1 << shift;                 // targets per bucket (<=256)
    int t0 = b << shift;
    int s0 = bbase[b];
    int s1 = (b == NB - 1) ? E : bbase[b + 1];
    int t = threadIdx.x;
    if (t < tpb) lh[t] = 0;
    __syncthreads();
    for (int e = s0 + t; e < s1; e += 256)
        atomicAdd(&lh[staged[e] >> 17], 1);
    __syncthreads();
    int v = (t < tpb) ? lh[t] : 0;
    sd[t] = v;
    __syncthreads();
    for (int off = 1; off < 256; off <<= 1) {
        int x = (t >= off) ? sd[t - off] : 0;
        __syncthreads();
        sd[t] += x;
        __syncthreads();
    }
    if (t < tpb) {
        int excl = sd[t] - v;
        lh[t] = excl;                      // reuse as local cursor
        int tg = t0 + t;
        if (tg < N) rs[tg] = s0 + excl;
    }
    if (b == NB - 1 && t == 0) rs[N] = E;
    __syncthreads();
    for (int e = s0 + t; e < s1; e += 256) {
        int w = staged[e];
        int lt = w >> 17;
        int src = w & 0x1FFFF;
        int p = s0 + atomicAdd(&lh[lt], 1);
        csr[p] = src;
    }
}

// ------------------------------------------------------------- aggregation

// Cast x to a padded fp16 [N][16] mirror (3.2 MB -> per-XCD-L2 resident).
__global__ void xcast_k(const float* __restrict__ x, __half* __restrict__ x16,
                        int N) {
    int i = blockIdx.x * blockDim.x + threadIdx.x;
    if (i >= N) return;
    const float* xr = x + (size_t)i * 9;
    union { _Float16 h[16]; uint4 u4[2]; } o;
    #pragma unroll
    for (int f = 0; f < 9; ++f) o.h[f] = (_Float16)xr[f];
    #pragma unroll
    for (int f = 9; f < 16; ++f) o.h[f] = (_Float16)0.f;
    uint4* dst = reinterpret_cast<uint4*>(x16 + (size_t)i * 16);
    dst[0] = o.u4[0];
    dst[1] = o.u4[1];
}

// Layer-1 aggregation + pack from the fp16 x mirror: one thread per node.
// Emits the fp16 A-row [mean9 | x9 | 0...0] for the K=32 MFMA GEMM.
__global__ void agg9pack_k(const __half* __restrict__ x16, const int* __restrict__ rs,
                           const int* __restrict__ csr, __half* __restrict__ a32,
                           int N) {
    int i = blockIdx.x * blockDim.x + threadIdx.x;
    if (i >= N) return;
    int s0 = rs[i], s1 = rs[i + 1];
    const uint4* h4 = reinterpret_cast<const uint4*>(x16);   // N x 2 uint4
    float a[9];
    #pragma unroll
    for (int f = 0; f < 9; ++f) a[f] = 0.f;
    auto acc9 = [&](int src) {
        uint4 va = h4[(size_t)src * 2];
        unsigned int wb = *reinterpret_cast<const unsigned int*>(
            x16 + (size_t)src * 16 + 8);
        const __half2* p = reinterpret_cast<const __half2*>(&va);
        #pragma unroll
        for (int q = 0; q < 4; ++q) {
            float2 f = __half22float2(p[q]);
            a[q * 2]     += f.x;
            a[q * 2 + 1] += f.y;
        }
        __half2 h8 = *reinterpret_cast<const __half2*>(&wb);
        a[8] += __half22float2(h8).x;
    };
    int j = s0;
    for (; j + 2 <= s1; j += 2) { acc9(csr[j]); acc9(csr[j + 1]); }
    if (j < s1) acc9(csr[j]);
    float inv = (s1 > s0) ? 1.f / (float)(s1 - s0) : 0.f;
    union { _Float16 h[32]; uint4 u4[4]; } o;
    #pragma unroll
    for (int f = 0; f < 9; ++f) o.h[f] = (_Float16)(a[f] * inv);
    const _Float16* sx = reinterpret_cast<const _Float16*>(x16 + (size_t)i * 16);
    #pragma unroll
    for (int f = 0; f < 9; ++f) o.h[9 + f] = sx[f];
    #pragma unroll
    for (int f = 18; f < 32; ++f) o.h[f] = (_Float16)0.f;
    uint4* dst = reinterpret_cast<uint4*>(a32 + (size_t)i * 32);
    #pragma unroll
    for (int q = 0; q < 4; ++q) dst[q] = o.u4[q];
}

// ------------------------------------------------------------------- GEMMs

// Pack fp32 W[K][N] into MFMA B-fragment order, fp16 (m89/m92 layout).
struct WPD { const float* W; _Float16* dst; int K, N; };
struct WPD6 { WPD d[6]; };

__global__ void wpack6_k(WPD6 all) {
    WPD w = all.d[blockIdx.y];
    int idx = blockIdx.x * blockDim.x + threadIdx.x;
    int kcb = w.K / 32;
    int total = (w.N / 16) * kcb * 64;
    if (idx >= total) return;
    int lane = idx & 63;
    int blk = idx >> 6;
    int kb = blk % kcb;
    int nf = blk / kcb;
    int col = nf * 16 + (lane & 15);
    int k0 = kb * 32 + (lane >> 4) * 8;
    f16x8 v;
    #pragma unroll
    for (int j = 0; j < 8; ++j)
        v[j] = (_Float16)w.W[(size_t)(k0 + j) * w.N + col];
    *reinterpret_cast<f16x8*>(w.dst + (size_t)idx * 8) = v;
}

// Pack layer-1 combined weight [W1l(9x128); W1r(9x128); 0...] as K=32, N=128.
__global__ void wpack1_k(const float* __restrict__ Wl, const float* __restrict__ Wr,
                         _Float16* __restrict__ wpk) {
    int idx = blockIdx.x * blockDim.x + threadIdx.x;
    if (idx >= 8 * 64) return;               // (N/16=8) * (KB=1) * 64
    int lane = idx & 63;
    int nf = idx >> 6;
    int col = nf * 16 + (lane & 15);
    int k0 = (lane >> 4) * 8;
    f16x8 v;
    #pragma unroll
    for (int j = 0; j < 8; ++j) {
        int k = k0 + j;
        float w = (k < 9) ? Wl[(size_t)k * 128 + col]
                : (k < 18) ? Wr[(size_t)(k - 9) * 128 + col] : 0.f;
        v[j] = (_Float16)w;
    }
    *reinterpret_cast<f16x8*>(wpk + (size_t)idx * 8) = v;
}

// MFMA fp16 GEMM: C[M,TN] = relu(A1@W1 (+ A2@W2) + bias), fp32 accum, fp16 out.
// Block: 64 rows x TN cols, 4 waves; wave owns NF 16-col frags; K = KK.
// Row-wise in-place (C == A1 or A2) is safe.
template<int NF, int NS, int KK>
__global__ __launch_bounds__(256) void mfma_lin_k(
        const __half* A1, const __half* A2,
        const _Float16* __restrict__ pk1, const _Float16* __restrict__ pk2,
        const float* __restrict__ bias, __half* C, int M) {
    constexpr int TN = 64 * NF;          // 128 or 64
    constexpr int KB = KK / 32;
    constexpr int LPR = KK / 8;          // uint4 loads per row
    constexpr int RPI = 256 / LPR;       // rows staged per iteration
    constexpr int ITER = 64 / RPI;
    __shared__ _Float16 a_lds[NS][64][KK + 8];

    int tid = threadIdx.x;
    int lane = tid & 63;
    int wave = tid >> 6;
    int rb = blockIdx.x * 64;

    const __half* As[2] = {A1, A2};
    #pragma unroll
    for (int s = 0; s < NS; ++s) {
        #pragma unroll
        for (int i = 0; i < ITER; ++i) {
            int row = (tid / LPR) + i * RPI;
            int c = tid % LPR;
            int grow = rb + row;
            uint4 v = make_uint4(0, 0, 0, 0);
            if (grow < M)
                v = reinterpret_cast<const uint4*>(As[s] + (size_t)grow * KK)[c];
            *reinterpret_cast<uint4*>(&a_lds[s][row][c * 8]) = v;
        }
    }

    const _Float16* pks[2] = {pk1, pk2};
    f16x8 bfrag[NS][KB][NF];
    #pragma unroll
    for (int s = 0; s < NS; ++s)
        #pragma unroll
        for (int kb = 0; kb < KB; ++kb)
            #pragma unroll
            for (int n = 0; n < NF; ++n) {
                int nf = wave * NF + n;
                bfrag[s][kb][n] =
                    reinterpret_cast<const f16x8*>(pks[s])[(size_t)(nf * KB + kb) * 64 + lane];
            }

    f32x4 acc[4][NF];
    #pragma unroll
    for (int m = 0; m < 4; ++m)
        #pragma unroll
        for (int n = 0; n < NF; ++n)
            acc[m][n] = (f32x4){0.f, 0.f, 0.f, 0.f};

    __syncthreads();

    #pragma unroll
    for (int s = 0; s < NS; ++s)
        #pragma unroll
        for (int kb = 0; kb < KB; ++kb)
            #pragma unroll
            for (int m = 0; m < 4; ++m) {
                f16x8 a = *reinterpret_cast<const f16x8*>(
                    &a_lds[s][m * 16 + (lane & 15)][kb * 32 + (lane >> 4) * 8]);
                #pragma unroll
                for (int n = 0; n < NF; ++n)
                    acc[m][n] = __builtin_amdgcn_mfma_f32_16x16x32_f16(
                        a, bfrag[s][kb][n], acc[m][n], 0, 0, 0);
            }

    #pragma unroll
    for (int n = 0; n < NF; ++n) {
        int col = wave * NF * 16 + n * 16 + (lane & 15);
        float bv = bias[col];
        #pragma unroll
        for (int m = 0; m < 4; ++m) {
            #pragma unroll
            for (int j = 0; j < 4; ++j) {
                int grow = rb + m * 16 + (lane >> 4) * 4 + j;
                if (grow < M) {
                    float v = fmaxf(acc[m][n][j] + bv, 0.f);
                    C[(size_t)grow * TN + col] = __float2half_rn(v);
                }
            }
        }
    }
}

// R15: fused SAGE layer — gather-mean(h[nbr]) directly into the A-operand
// LDS tile (no agg16 global round trip, no inter-kernel barrier), then dual
// MFMA: hout = relu(mean_lds @ Wl + self_lds @ Wr + b). OUTPUT MUST BE A
// DIFFERENT BUFFER than hin (other blocks still gather hin rows — ping-pong).
// Arithmetic identical to agg128h4_k + mfma_lin_k<2,2,128> (same summation
// order, fp16 rounding at the same point).
__global__ __launch_bounds__(256) void agg_gemm_k(
        const __half* __restrict__ hin,
        const int* __restrict__ rs, const int* __restrict__ csr,
        const _Float16* __restrict__ pkl, const _Float16* __restrict__ pkr,
        const float* __restrict__ bias, __half* __restrict__ hout, int M) {
    constexpr int KK = 128;
    __shared__ _Float16 a_lds[2][64][KK + 8];

    int tid = threadIdx.x;
    int lane = tid & 63;
    int wave = tid >> 6;
    int rb = blockIdx.x * 64;
    int l16 = lane & 15;

    // stage self rows -> a_lds[1] (streaming, 16B/lane)
    #pragma unroll
    for (int i = 0; i < 4; ++i) {
        int row = (tid >> 4) + i * 16;
        int grow = rb + row;
        uint4 v = make_uint4(0, 0, 0, 0);
        if (grow < M)
            v = reinterpret_cast<const uint4*>(hin + (size_t)grow * KK)[l16];
        *reinterpret_cast<uint4*>(&a_lds[1][row][l16 * 8]) = v;
    }

    // gather-mean neighbors -> a_lds[0]; 4 nodes/wave-iter, 16 lanes/node
    const uint4* h4 = reinterpret_cast<const uint4*>(hin);
    #pragma unroll
    for (int it = 0; it < 4; ++it) {
        int row = wave * 16 + it * 4 + (lane >> 4);
        int node = rb + row;
        float acc[8];
        #pragma unroll
        for (int c = 0; c < 8; ++c) acc[c] = 0.f;
        int s0 = 0, s1 = 0;
        if (node < M) { s0 = rs[node]; s1 = rs[node + 1]; }
        int j = s0;
        for (; j + 4 <= s1; j += 4) {
            uint4 v[4];
            #pragma unroll
            for (int u = 0; u < 4; ++u)
                v[u] = h4[(size_t)csr[j + u] * 16 + l16];
            #pragma unroll
            for (int u = 0; u < 4; ++u) {
                const __half2* p = reinterpret_cast<const __half2*>(&v[u]);
                #pragma unroll
                for (int q = 0; q < 4; ++q) {
                    float2 f = __half22float2(p[q]);
                    acc[q * 2]     += f.x;
                    acc[q * 2 + 1] += f.y;
                }
            }
        }
        for (; j < s1; ++j) {
            uint4 vv = h4[(size_t)csr[j] * 16 + l16];
            const __half2* p = reinterpret_cast<const __half2*>(&vv);
            #pragma unroll
            for (int q = 0; q < 4; ++q) {
                float2 f = __half22float2(p[q]);
                acc[q * 2]     += f.x;
                acc[q * 2 + 1] += f.y;
            }
        }
        float inv = (s1 > s0) ? 1.f / (float)(s1 - s0) : 0.f;
        __half2 o[4];
        #pragma unroll
        for (int q = 0; q < 4; ++q)
            o[q] = __floats2half2_rn(acc[q * 2] * inv, acc[q * 2 + 1] * inv);
        *reinterpret_cast<uint4*>(&a_lds[0][row][l16 * 8]) =
            *reinterpret_cast<uint4*>(o);
    }

    // B fragments (L2-resident packed weights)
    const _Float16* pks[2] = {pkl, pkr};
    f16x8 bfrag[2][4][2];
    #pragma unroll
    for (int s = 0; s < 2; ++s)
        #pragma unroll
        for (int kb = 0; kb < 4; ++kb)
            #pragma unroll
            for (int n = 0; n < 2; ++n) {
                int nf = wave * 2 + n;
                bfrag[s][kb][n] =
                    reinterpret_cast<const f16x8*>(pks[s])[(size_t)(nf * 4 + kb) * 64 + lane];
            }

    f32x4 acc[4][2];
    #pragma unroll
    for (int m = 0; m < 4; ++m)
        #pragma unroll
        for (int n = 0; n < 2; ++n)
            acc[m][n] = (f32x4){0.f, 0.f, 0.f, 0.f};

    __syncthreads();

    #pragma unroll
    for (int s = 0; s < 2; ++s)
        #pragma unroll
        for (int kb = 0; kb < 4; ++kb)
            #pragma unroll
            for (int m = 0; m < 4; ++m) {
                f16x8 a = *reinterpret_cast<const f16x8*>(
                    &a_lds[s][m * 16 + (lane & 15)][kb * 32 + (lane >> 4) * 8]);
                #pragma unroll
                for (int n = 0; n < 2; ++n)
                    acc[m][n] = __builtin_amdgcn_mfma_f32_16x16x32_f16(
                        a, bfrag[s][kb][n], acc[m][n], 0, 0, 0);
            }

    #pragma unroll
    for (int n = 0; n < 2; ++n) {
        int col = wave * 32 + n * 16 + (lane & 15);
        float bv = bias[col];
        #pragma unroll
        for (int m = 0; m < 4; ++m) {
            #pragma unroll
            for (int j = 0; j < 4; ++j) {
                int grow = rb + m * 16 + (lane >> 4) * 4 + j;
                if (grow < M) {
                    float v = fmaxf(acc[m][n][j] + bv, 0.f);
                    hout[(size_t)grow * 128 + col] = __float2half_rn(v);
                }
            }
        }
    }
}

// Fused tail — MLP2 (128->64, relu) + final 64->3 matvec + log_softmax.
__global__ __launch_bounds__(256) void mfma_lin_final_k(
        const __half* A1, const _Float16* __restrict__ pk1,
        const float* __restrict__ bias,
        const float* __restrict__ W3, const float* __restrict__ b3,
        float* __restrict__ outp, int M) {
    constexpr int KK = 128;
    __shared__ _Float16 a_lds[64][136];
    __shared__ float smem[64][68];

    int tid = threadIdx.x;
    int lane = tid & 63;
    int wave = tid >> 6;
    int rb = blockIdx.x * 64;

    #pragma unroll
    for (int i = 0; i < 4; ++i) {
        int row = (tid >> 4) + i * 16;
        int grow = rb + row;
        uint4 v = make_uint4(0, 0, 0, 0);
        if (grow < M)
            v = reinterpret_cast<const uint4*>(A1 + (size_t)grow * KK)[tid & 15];
        *reinterpret_cast<uint4*>(&a_lds[row][(tid & 15) * 8]) = v;
    }

    f16x8 bfrag[4];
    #pragma unroll
    for (int kb = 0; kb < 4; ++kb)
        bfrag[kb] = reinterpret_cast<const f16x8*>(pk1)[(size_t)(wave * 4 + kb) * 64 + lane];

    f32x4 acc[4];
    #pragma unroll
    for (int m = 0; m < 4; ++m) acc[m] = (f32x4){0.f, 0.f, 0.f, 0.f};

    __syncthreads();

    #pragma unroll
    for (int kb = 0; kb < 4; ++kb)
        #pragma unroll
        for (int m = 0; m < 4; ++m) {
            f16x8 a = *reinterpret_cast<const f16x8*>(
                &a_lds[m * 16 + (lane & 15)][kb * 32 + (lane >> 4) * 8]);
            acc[m] = __builtin_amdgcn_mfma_f32_16x16x32_f16(a, bfrag[kb], acc[m], 0, 0, 0);
        }

    int col = wave * 16 + (lane & 15);
    float bv = bias[col];
    #pragma unroll
    for (int m = 0; m < 4; ++m)
        #pragma unroll
        for (int j = 0; j < 4; ++j) {
            int row = m * 16 + (lane >> 4) * 4 + j;
            smem[row][col] = fmaxf(acc[m][j] + bv, 0.f);
        }
    __syncthreads();

    if (tid < 64) {
        int grow = rb + tid;
        if (grow < M) {
            float l0 = b3[0], l1 = b3[1], l2 = b3[2];
            #pragma unroll 8
            for (int k = 0; k < 64; ++k) {
                float v = smem[tid][k];
                l0 = fmaf(v, W3[k * 3 + 0], l0);
                l1 = fmaf(v, W3[k * 3 + 1], l1);
                l2 = fmaf(v, W3[k * 3 + 2], l2);
            }
            float mx = fmaxf(l0, fmaxf(l1, l2));
            float e0 = expf(l0 - mx), e1 = expf(l1 - mx), e2 = expf(l2 - mx);
            float lse = logf(e0 + e1 + e2) + mx;
            outp[(size_t)grow * 3 + 0] = l0 - lse;
            outp[(size_t)grow * 3 + 1] = l1 - lse;
            outp[(size_t)grow * 3 + 2] = l2 - lse;
        }
    }
}

// ------------------------------------------------------------------ launch

extern "C" void kernel_launch(void* const* d_in, const int* in_sizes, int n_in,
                              void* d_out, int out_size, void* d_ws, size_t ws_size,
                              hipStream_t stream) {
    const float* x   = (const float*)d_in[0];
    const int* ei    = (const int*)d_in[1];   // int32 (harness-converted)
    const float* W1l = (const float*)d_in[2];
    const float* b1  = (const float*)d_in[3];
    const float* W1r = (const float*)d_in[4];
    const float* W2l = (const float*)d_in[5];
    const float* b2  = (const float*)d_in[6];
    const float* W2r = (const float*)d_in[7];
    const float* W3l = (const float*)d_in[8];
    const float* b3  = (const float*)d_in[9];
    const float* W3r = (const float*)d_in[10];
    const float* Wl1 = (const float*)d_in[11];
    const float* bl1 = (const float*)d_in[12];
    const float* Wl2 = (const float*)d_in[13];
    const float* bl2 = (const float*)d_in[14];
    const float* Wl3 = (const float*)d_in[15];
    const float* bl3 = (const float*)d_in[16];
    float* out = (float*)d_out;

    const int N = in_sizes[0] / 9;
    const int E = in_sizes[1] / 2;

    char* ws = (char*)d_ws;
    size_t off = 0;
    auto alloc = [&](size_t bytes) -> void* {
        void* p = ws + off;
        off += (bytes + 255) & ~(size_t)255;
        return p;
    };
    __half* h16    = (__half*)alloc((size_t)N * 128 * sizeof(__half));  // 25.6 MB
    __half* hb     = (__half*)alloc((size_t)N * 128 * sizeof(__half));  // 25.6 MB (ping-pong)
    __half* a32    = (__half*)alloc((size_t)N * 32 * sizeof(__half));   // 6.4 MB
    __half* x16    = (__half*)alloc((size_t)N * 16 * sizeof(__half));   // 3.2 MB
    int* rs     = (int*)alloc((size_t)(N + 1) * sizeof(int));
    int* csr    = (int*)alloc((size_t)E * sizeof(int));                  // 6.4 MB
    int* staged = (int*)alloc((size_t)E * sizeof(int));                  // 6.4 MB
    _Float16* wpk1  = (_Float16*)alloc(32 * 128 * sizeof(_Float16));
    _Float16* wpk2l = (_Float16*)alloc(128 * 128 * sizeof(_Float16));
    _Float16* wpk2r = (_Float16*)alloc(128 * 128 * sizeof(_Float16));
    _Float16* wpk3l = (_Float16*)alloc(128 * 128 * sizeof(_Float16));
    _Float16* wpk3r = (_Float16*)alloc(128 * 128 * sizeof(_Float16));
    _Float16* wpkl1 = (_Float16*)alloc(128 * 128 * sizeof(_Float16));
    _Float16* wpkl2 = (_Float16*)alloc(128 * 64 * sizeof(_Float16));
    (void)ws_size; (void)n_in; (void)out_size;

    // bucket params (N=100K, E=1.6M -> shift=7, NB=782, NBLK=782)
    int shift = 7;
    while ((((size_t)N + ((size_t)1 << shift) - 1) >> shift) > MAXNB) ++shift;
    const int NB = (N + (1 << shift) - 1) >> shift;
    const int NBLK = (E + CH - 1) / CH;               // <= 1024 (scan capacity)
    int* bh    = (int*)alloc((size_t)NB * NBLK * sizeof(int));          // 2.4 MB
    int* btot  = (int*)alloc((size_t)NB * sizeof(int));
    int* bbase = (int*)alloc((size_t)(NB + 1) * sizeof(int));
    int* bsum  = (int*)alloc(64 * sizeof(int));

    // Weight packing + x fp16 mirror (independent of CSR build)
    WPD6 wp;
    wp.d[0] = {W2l, wpk2l, 128, 128};
    wp.d[1] = {W2r, wpk2r, 128, 128};
    wp.d[2] = {W3l, wpk3l, 128, 128};
    wp.d[3] = {W3r, wpk3r, 128, 128};
    wp.d[4] = {Wl1, wpkl1, 128, 128};
    wp.d[5] = {Wl2, wpkl2, 128, 64};
    wpack6_k<<<dim3(8, 6), 256, 0, stream>>>(wp);
    wpack1_k<<<2, 256, 0, stream>>>(W1l, W1r, wpk1);
    xcast_k<<<(N + 255) / 256, 256, 0, stream>>>(x, x16, N);

    // CSR build (two-level bucket, no global-atomic scatter)
    bhist_k<<<NBLK, 256, 0, stream>>>(ei, bh, E, shift, NB, NBLK);
    scan_col_k<<<NB, 256, 0, stream>>>(bh, btot, NBLK, NB);
    scan_block_k<<<1, 256, 0, stream>>>(btot, bbase, bsum, NB);
    bscatter_k<<<NBLK, 256, 0, stream>>>(ei, bh, bbase, staged, E, shift, NB, NBLK);
    csrfill_k<<<NB, 256, 0, stream>>>(staged, bbase, rs, csr, N, E, shift, NB);

    const int gemm_grid = (N + 63) / 64;

    // SAGE layer 1 (9 -> 128): pack [mean9|x9|0] fp16, then K=32 MFMA GEMM
    agg9pack_k<<<(N + 255) / 256, 256, 0, stream>>>(x16, rs, csr, a32, N);
    mfma_lin_k<2, 1, 32><<<gemm_grid, 256, 0, stream>>>(
        a32, nullptr, wpk1, nullptr, b1, h16, N);

    // SAGE layer 2 (fused gather+GEMM): h2 = relu(mean(h1[nbr])@W2l + h1@W2r + b2)
    agg_gemm_k<<<gemm_grid, 256, 0, stream>>>(
        h16, rs, csr, wpk2l, wpk2r, b2, hb, N);

    // SAGE layer 3 (fused): h3 = relu(mean(h2[nbr])@W3l + h2@W3r + b3)
    agg_gemm_k<<<gemm_grid, 256, 0, stream>>>(
        hb, rs, csr, wpk3l, wpk3r, b3, h16, N);

    // MLP: 128 -> 128 (relu) GEMM, then fused {128->64 relu GEMM + 64->3 +
    // log_softmax} tail
    mfma_lin_k<2, 1, 128><<<gemm_grid, 256, 0, stream>>>(
        h16, nullptr, wpkl1, nullptr, bl1, h16, N);
    mfma_lin_final_k<<<gemm_grid, 256, 0, stream>>>(
        h16, wpkl2, bl2, Wl3, bl3, out, N);
}

// Round 16
// 289.545 us; speedup vs baseline: 1.0120x; 1.0120x over previous
//
#include <hip/hip_runtime.h>
#include <hip/hip_fp16.h>
#include <stdint.h>

typedef _Float16 f16x8 __attribute__((ext_vector_type(8)));
typedef float f32x4 __attribute__((ext_vector_type(4)));

// ---------------------------------------------------------------- CSR build
// edge_index arrives as int32 (harness converts integer inputs to int32).
// R4: deterministic two-level bucket CSR build (no global-atomic scatter).
// R13: R11's measured-best config (CH=2048, shift=7 -> 782 blocks).
// R16: reverted R15's agg+GEMM fusion (84us vs 75us break-even: 34.8KB LDS
// -> 4 blocks/CU -> gather occupancy 33% vs 68%; gather throughput is
// CU-level-outstanding-requests bound — third confirmation after R8/R10).

#define CH 2048           // edges per block in bucket passes
#define MAXNB 1024        // max bucket count supported by LDS arrays

__global__ __launch_bounds__(256) void bhist_k(const int* __restrict__ ei,
        int* __restrict__ bh, int E, int shift, int NB, int NBLK) {
    __shared__ int lh[MAXNB];
    for (int b = threadIdx.x; b < NB; b += 256) lh[b] = 0;
    __syncthreads();
    int base = blockIdx.x * CH;
    int end = min(base + CH, E);
    for (int e = base + threadIdx.x; e < end; e += 256) {
        int t = ei[(size_t)E + e];
        atomicAdd(&lh[t >> shift], 1);
    }
    __syncthreads();
    for (int b = threadIdx.x; b < NB; b += 256)
        bh[(size_t)b * NBLK + blockIdx.x] = lh[b];   // column-major per bucket
}

// Exclusive scan of each bucket's per-block counts (NBLK <= 1024).
__global__ __launch_bounds__(256) void scan_col_k(int* bh, int* __restrict__ btot,
                                                  int NBLK, int NB) {
    __shared__ int sd[256];
    size_t rowoff = (size_t)blockIdx.x * NBLK;
    int t = threadIdx.x;
    int base = t * 4;
    int v0 = (base + 0 < NBLK) ? bh[rowoff + base + 0] : 0;
    int v1 = (base + 1 < NBLK) ? bh[rowoff + base + 1] : 0;
    int v2 = (base + 2 < NBLK) ? bh[rowoff + base + 2] : 0;
    int v3 = (base + 3 < NBLK) ? bh[rowoff + base + 3] : 0;
    int s = v0 + v1 + v2 + v3;
    sd[t] = s;
    __syncthreads();
    for (int off = 1; off < 256; off <<= 1) {
        int x = (t >= off) ? sd[t - off] : 0;
        __syncthreads();
        sd[t] += x;
        __syncthreads();
    }
    int ex = sd[t] - s;
    if (base + 0 < NBLK) bh[rowoff + base + 0] = ex;
    if (base + 1 < NBLK) bh[rowoff + base + 1] = ex + v0;
    if (base + 2 < NBLK) bh[rowoff + base + 2] = ex + v0 + v1;
    if (base + 3 < NBLK) bh[rowoff + base + 3] = ex + v0 + v1 + v2;
    if (t == 255) btot[blockIdx.x] = sd[255];
}

__global__ void scan_block_k(const int* __restrict__ deg, int* __restrict__ excl,
                             int* __restrict__ bsum, int N) {
    __shared__ int sd[256];
    int t = threadIdx.x;
    int base = blockIdx.x * 1024 + t * 4;
    int v0 = (base + 0 < N) ? deg[base + 0] : 0;
    int v1 = (base + 1 < N) ? deg[base + 1] : 0;
    int v2 = (base + 2 < N) ? deg[base + 2] : 0;
    int v3 = (base + 3 < N) ? deg[base + 3] : 0;
    int s = v0 + v1 + v2 + v3;
    sd[t] = s;
    __syncthreads();
    for (int off = 1; off < 256; off <<= 1) {
        int x = (t >= off) ? sd[t - off] : 0;
        __syncthreads();
        sd[t] += x;
        __syncthreads();
    }
    int incl = sd[t];
    int ex = incl - s;
    if (base + 0 < N) excl[base + 0] = ex;
    if (base + 1 < N) excl[base + 1] = ex + v0;
    if (base + 2 < N) excl[base + 2] = ex + v0 + v1;
    if (base + 3 < N) excl[base + 3] = ex + v0 + v1 + v2;
    if (t == 255) bsum[blockIdx.x] = incl;
}

__global__ __launch_bounds__(256) void bscatter_k(const int* __restrict__ ei,
        const int* __restrict__ bh, const int* __restrict__ bbase,
        int* __restrict__ staged, int E, int shift, int NB, int NBLK) {
    __shared__ int cur[MAXNB];
    for (int b = threadIdx.x; b < NB; b += 256)
        cur[b] = bbase[b] + bh[(size_t)b * NBLK + blockIdx.x];
    __syncthreads();
    int base = blockIdx.x * CH;
    int end = min(base + CH, E);
    int mask = (1 << shift) - 1;
    for (int e = base + threadIdx.x; e < end; e += 256) {
        int s = ei[e];
        int t = ei[(size_t)E + e];
        int p = atomicAdd(&cur[t >> shift], 1);
        staged[p] = s | ((t & mask) << 17);
    }
}

__global__ __launch_bounds__(256) void csrfill_k(const int* __restrict__ staged,
        const int* __restrict__ bbase, int* __restrict__ rs, int* __restrict__ csr,
        int N, int E, int shift, int NB) {
    __shared__ int lh[256];
    __shared__ int sd[256];
    int b = blockIdx.x;
    int tpb = 1 << shift;                 // targets per bucket (<=256)
    int t0 = b << shift;
    int s0 = bbase[b];
    int s1 = (b == NB - 1) ? E : bbase[b + 1];
    int t = threadIdx.x;
    if (t < tpb) lh[t] = 0;
    __syncthreads();
    for (int e = s0 + t; e < s1; e += 256)
        atomicAdd(&lh[staged[e] >> 17], 1);
    __syncthreads();
    int v = (t < tpb) ? lh[t] : 0;
    sd[t] = v;
    __syncthreads();
    for (int off = 1; off < 256; off <<= 1) {
        int x = (t >= off) ? sd[t - off] : 0;
        __syncthreads();
        sd[t] += x;
        __syncthreads();
    }
    if (t < tpb) {
        int excl = sd[t] - v;
        lh[t] = excl;                      // reuse as local cursor
        int tg = t0 + t;
        if (tg < N) rs[tg] = s0 + excl;
    }
    if (b == NB - 1 && t == 0) rs[N] = E;
    __syncthreads();
    for (int e = s0 + t; e < s1; e += 256) {
        int w = staged[e];
        int lt = w >> 17;
        int src = w & 0x1FFFF;
        int p = s0 + atomicAdd(&lh[lt], 1);
        csr[p] = src;
    }
}

// ------------------------------------------------------------- aggregation

// Cast x to a padded fp16 [N][16] mirror (3.2 MB -> per-XCD-L2 resident).
__global__ void xcast_k(const float* __restrict__ x, __half* __restrict__ x16,
                        int N) {
    int i = blockIdx.x * blockDim.x + threadIdx.x;
    if (i >= N) return;
    const float* xr = x + (size_t)i * 9;
    union { _Float16 h[16]; uint4 u4[2]; } o;
    #pragma unroll
    for (int f = 0; f < 9; ++f) o.h[f] = (_Float16)xr[f];
    #pragma unroll
    for (int f = 9; f < 16; ++f) o.h[f] = (_Float16)0.f;
    uint4* dst = reinterpret_cast<uint4*>(x16 + (size_t)i * 16);
    dst[0] = o.u4[0];
    dst[1] = o.u4[1];
}

// Layer-1 aggregation + pack from the fp16 x mirror: one thread per node.
// Emits the fp16 A-row [mean9 | x9 | 0...0] for the K=32 MFMA GEMM.
__global__ void agg9pack_k(const __half* __restrict__ x16, const int* __restrict__ rs,
                           const int* __restrict__ csr, __half* __restrict__ a32,
                           int N) {
    int i = blockIdx.x * blockDim.x + threadIdx.x;
    if (i >= N) return;
    int s0 = rs[i], s1 = rs[i + 1];
    const uint4* h4 = reinterpret_cast<const uint4*>(x16);   // N x 2 uint4
    float a[9];
    #pragma unroll
    for (int f = 0; f < 9; ++f) a[f] = 0.f;
    auto acc9 = [&](int src) {
        uint4 va = h4[(size_t)src * 2];
        unsigned int wb = *reinterpret_cast<const unsigned int*>(
            x16 + (size_t)src * 16 + 8);
        const __half2* p = reinterpret_cast<const __half2*>(&va);
        #pragma unroll
        for (int q = 0; q < 4; ++q) {
            float2 f = __half22float2(p[q]);
            a[q * 2]     += f.x;
            a[q * 2 + 1] += f.y;
        }
        __half2 h8 = *reinterpret_cast<const __half2*>(&wb);
        a[8] += __half22float2(h8).x;
    };
    int j = s0;
    for (; j + 2 <= s1; j += 2) { acc9(csr[j]); acc9(csr[j + 1]); }
    if (j < s1) acc9(csr[j]);
    float inv = (s1 > s0) ? 1.f / (float)(s1 - s0) : 0.f;
    union { _Float16 h[32]; uint4 u4[4]; } o;
    #pragma unroll
    for (int f = 0; f < 9; ++f) o.h[f] = (_Float16)(a[f] * inv);
    const _Float16* sx = reinterpret_cast<const _Float16*>(x16 + (size_t)i * 16);
    #pragma unroll
    for (int f = 0; f < 9; ++f) o.h[9 + f] = sx[f];
    #pragma unroll
    for (int f = 18; f < 32; ++f) o.h[f] = (_Float16)0.f;
    uint4* dst = reinterpret_cast<uint4*>(a32 + (size_t)i * 32);
    #pragma unroll
    for (int q = 0; q < 4; ++q) dst[q] = o.u4[q];
}

// F=128 fp16 aggregation: 4 nodes per wave, 16 lanes per row, uint4 (16B)/lane.
// Established floor (R8/R10/R15 null results): random-gather delivery is
// bound by CU-level outstanding requests; 57us/dispatch is the ceiling here.
__global__ __launch_bounds__(256) void agg128h4_k(const __half* __restrict__ h16,
        const int* __restrict__ rs, const int* __restrict__ csr,
        __half* __restrict__ out, int N) {
    int l16 = threadIdx.x & 15;
    int node = blockIdx.x * 16 + (threadIdx.x >> 4);
    if (node >= N) return;
    int s0 = rs[node], s1 = rs[node + 1];
    const uint4* h4 = reinterpret_cast<const uint4*>(h16);   // N x 16 uint4
    float acc[8];
    #pragma unroll
    for (int c = 0; c < 8; ++c) acc[c] = 0.f;
    int j = s0;
    for (; j + 4 <= s1; j += 4) {
        uint4 v[4];
        #pragma unroll
        for (int u = 0; u < 4; ++u)
            v[u] = h4[(size_t)csr[j + u] * 16 + l16];
        #pragma unroll
        for (int u = 0; u < 4; ++u) {
            const __half2* p = reinterpret_cast<const __half2*>(&v[u]);
            #pragma unroll
            for (int q = 0; q < 4; ++q) {
                float2 f = __half22float2(p[q]);
                acc[q * 2]     += f.x;
                acc[q * 2 + 1] += f.y;
            }
        }
    }
    for (; j < s1; ++j) {
        uint4 vv = h4[(size_t)csr[j] * 16 + l16];
        const __half2* p = reinterpret_cast<const __half2*>(&vv);
        #pragma unroll
        for (int q = 0; q < 4; ++q) {
            float2 f = __half22float2(p[q]);
            acc[q * 2]     += f.x;
            acc[q * 2 + 1] += f.y;
        }
    }
    float inv = (s1 > s0) ? 1.f / (float)(s1 - s0) : 0.f;
    __half2 o[4];
    #pragma unroll
    for (int q = 0; q < 4; ++q)
        o[q] = __floats2half2_rn(acc[q * 2] * inv, acc[q * 2 + 1] * inv);
    reinterpret_cast<uint4*>(out)[(size_t)node * 16 + l16] =
        *reinterpret_cast<uint4*>(o);
}

// ------------------------------------------------------------------- GEMMs

// Pack fp32 W[K][N] into MFMA B-fragment order, fp16 (m89/m92 layout).
struct WPD { const float* W; _Float16* dst; int K, N; };
struct WPD6 { WPD d[6]; };

__global__ void wpack6_k(WPD6 all) {
    WPD w = all.d[blockIdx.y];
    int idx = blockIdx.x * blockDim.x + threadIdx.x;
    int kcb = w.K / 32;
    int total = (w.N / 16) * kcb * 64;
    if (idx >= total) return;
    int lane = idx & 63;
    int blk = idx >> 6;
    int kb = blk % kcb;
    int nf = blk / kcb;
    int col = nf * 16 + (lane & 15);
    int k0 = kb * 32 + (lane >> 4) * 8;
    f16x8 v;
    #pragma unroll
    for (int j = 0; j < 8; ++j)
        v[j] = (_Float16)w.W[(size_t)(k0 + j) * w.N + col];
    *reinterpret_cast<f16x8*>(w.dst + (size_t)idx * 8) = v;
}

// Pack layer-1 combined weight [W1l(9x128); W1r(9x128); 0...] as K=32, N=128.
__global__ void wpack1_k(const float* __restrict__ Wl, const float* __restrict__ Wr,
                         _Float16* __restrict__ wpk) {
    int idx = blockIdx.x * blockDim.x + threadIdx.x;
    if (idx >= 8 * 64) return;               // (N/16=8) * (KB=1) * 64
    int lane = idx & 63;
    int nf = idx >> 6;
    int col = nf * 16 + (lane & 15);
    int k0 = (lane >> 4) * 8;
    f16x8 v;
    #pragma unroll
    for (int j = 0; j < 8; ++j) {
        int k = k0 + j;
        float w = (k < 9) ? Wl[(size_t)k * 128 + col]
                : (k < 18) ? Wr[(size_t)(k - 9) * 128 + col] : 0.f;
        v[j] = (_Float16)w;
    }
    *reinterpret_cast<f16x8*>(wpk + (size_t)idx * 8) = v;
}

// MFMA fp16 GEMM: C[M,TN] = relu(A1@W1 (+ A2@W2) + bias), fp32 accum, fp16 out.
// Block: 64 rows x TN cols, 4 waves; wave owns NF 16-col frags; K = KK.
// Row-wise in-place (C == A1 or A2) is safe.
template<int NF, int NS, int KK>
__global__ __launch_bounds__(256) void mfma_lin_k(
        const __half* A1, const __half* A2,
        const _Float16* __restrict__ pk1, const _Float16* __restrict__ pk2,
        const float* __restrict__ bias, __half* C, int M) {
    constexpr int TN = 64 * NF;          // 128 or 64
    constexpr int KB = KK / 32;
    constexpr int LPR = KK / 8;          // uint4 loads per row
    constexpr int RPI = 256 / LPR;       // rows staged per iteration
    constexpr int ITER = 64 / RPI;
    __shared__ _Float16 a_lds[NS][64][KK + 8];

    int tid = threadIdx.x;
    int lane = tid & 63;
    int wave = tid >> 6;
    int rb = blockIdx.x * 64;

    const __half* As[2] = {A1, A2};
    #pragma unroll
    for (int s = 0; s < NS; ++s) {
        #pragma unroll
        for (int i = 0; i < ITER; ++i) {
            int row = (tid / LPR) + i * RPI;
            int c = tid % LPR;
            int grow = rb + row;
            uint4 v = make_uint4(0, 0, 0, 0);
            if (grow < M)
                v = reinterpret_cast<const uint4*>(As[s] + (size_t)grow * KK)[c];
            *reinterpret_cast<uint4*>(&a_lds[s][row][c * 8]) = v;
        }
    }

    const _Float16* pks[2] = {pk1, pk2};
    f16x8 bfrag[NS][KB][NF];
    #pragma unroll
    for (int s = 0; s < NS; ++s)
        #pragma unroll
        for (int kb = 0; kb < KB; ++kb)
            #pragma unroll
            for (int n = 0; n < NF; ++n) {
                int nf = wave * NF + n;
                bfrag[s][kb][n] =
                    reinterpret_cast<const f16x8*>(pks[s])[(size_t)(nf * KB + kb) * 64 + lane];
            }

    f32x4 acc[4][NF];
    #pragma unroll
    for (int m = 0; m < 4; ++m)
        #pragma unroll
        for (int n = 0; n < NF; ++n)
            acc[m][n] = (f32x4){0.f, 0.f, 0.f, 0.f};

    __syncthreads();

    #pragma unroll
    for (int s = 0; s < NS; ++s)
        #pragma unroll
        for (int kb = 0; kb < KB; ++kb)
            #pragma unroll
            for (int m = 0; m < 4; ++m) {
                f16x8 a = *reinterpret_cast<const f16x8*>(
                    &a_lds[s][m * 16 + (lane & 15)][kb * 32 + (lane >> 4) * 8]);
                #pragma unroll
                for (int n = 0; n < NF; ++n)
                    acc[m][n] = __builtin_amdgcn_mfma_f32_16x16x32_f16(
                        a, bfrag[s][kb][n], acc[m][n], 0, 0, 0);
            }

    #pragma unroll
    for (int n = 0; n < NF; ++n) {
        int col = wave * NF * 16 + n * 16 + (lane & 15);
        float bv = bias[col];
        #pragma unroll
        for (int m = 0; m < 4; ++m) {
            #pragma unroll
            for (int j = 0; j < 4; ++j) {
                int grow = rb + m * 16 + (lane >> 4) * 4 + j;
                if (grow < M) {
                    float v = fmaxf(acc[m][n][j] + bv, 0.f);
                    C[(size_t)grow * TN + col] = __float2half_rn(v);
                }
            }
        }
    }
}

// Fused tail — MLP2 (128->64, relu) + final 64->3 matvec + log_softmax.
__global__ __launch_bounds__(256) void mfma_lin_final_k(
        const __half* A1, const _Float16* __restrict__ pk1,
        const float* __restrict__ bias,
        const float* __restrict__ W3, const float* __restrict__ b3,
        float* __restrict__ outp, int M) {
    constexpr int KK = 128;
    __shared__ _Float16 a_lds[64][136];
    __shared__ float smem[64][68];

    int tid = threadIdx.x;
    int lane = tid & 63;
    int wave = tid >> 6;
    int rb = blockIdx.x * 64;

    #pragma unroll
    for (int i = 0; i < 4; ++i) {
        int row = (tid >> 4) + i * 16;
        int grow = rb + row;
        uint4 v = make_uint4(0, 0, 0, 0);
        if (grow < M)
            v = reinterpret_cast<const uint4*>(A1 + (size_t)grow * KK)[tid & 15];
        *reinterpret_cast<uint4*>(&a_lds[row][(tid & 15) * 8]) = v;
    }

    f16x8 bfrag[4];
    #pragma unroll
    for (int kb = 0; kb < 4; ++kb)
        bfrag[kb] = reinterpret_cast<const f16x8*>(pk1)[(size_t)(wave * 4 + kb) * 64 + lane];

    f32x4 acc[4];
    #pragma unroll
    for (int m = 0; m < 4; ++m) acc[m] = (f32x4){0.f, 0.f, 0.f, 0.f};

    __syncthreads();

    #pragma unroll
    for (int kb = 0; kb < 4; ++kb)
        #pragma unroll
        for (int m = 0; m < 4; ++m) {
            f16x8 a = *reinterpret_cast<const f16x8*>(
                &a_lds[m * 16 + (lane & 15)][kb * 32 + (lane >> 4) * 8]);
            acc[m] = __builtin_amdgcn_mfma_f32_16x16x32_f16(a, bfrag[kb], acc[m], 0, 0, 0);
        }

    int col = wave * 16 + (lane & 15);
    float bv = bias[col];
    #pragma unroll
    for (int m = 0; m < 4; ++m)
        #pragma unroll
        for (int j = 0; j < 4; ++j) {
            int row = m * 16 + (lane >> 4) * 4 + j;
            smem[row][col] = fmaxf(acc[m][j] + bv, 0.f);
        }
    __syncthreads();

    if (tid < 64) {
        int grow = rb + tid;
        if (grow < M) {
            float l0 = b3[0], l1 = b3[1], l2 = b3[2];
            #pragma unroll 8
            for (int k = 0; k < 64; ++k) {
                float v = smem[tid][k];
                l0 = fmaf(v, W3[k * 3 + 0], l0);
                l1 = fmaf(v, W3[k * 3 + 1], l1);
                l2 = fmaf(v, W3[k * 3 + 2], l2);
            }
            float mx = fmaxf(l0, fmaxf(l1, l2));
            float e0 = expf(l0 - mx), e1 = expf(l1 - mx), e2 = expf(l2 - mx);
            float lse = logf(e0 + e1 + e2) + mx;
            outp[(size_t)grow * 3 + 0] = l0 - lse;
            outp[(size_t)grow * 3 + 1] = l1 - lse;
            outp[(size_t)grow * 3 + 2] = l2 - lse;
        }
    }
}

// ------------------------------------------------------------------ launch

extern "C" void kernel_launch(void* const* d_in, const int* in_sizes, int n_in,
                              void* d_out, int out_size, void* d_ws, size_t ws_size,
                              hipStream_t stream) {
    const float* x   = (const float*)d_in[0];
    const int* ei    = (const int*)d_in[1];   // int32 (harness-converted)
    const float* W1l = (const float*)d_in[2];
    const float* b1  = (const float*)d_in[3];
    const float* W1r = (const float*)d_in[4];
    const float* W2l = (const float*)d_in[5];
    const float* b2  = (const float*)d_in[6];
    const float* W2r = (const float*)d_in[7];
    const float* W3l = (const float*)d_in[8];
    const float* b3  = (const float*)d_in[9];
    const float* W3r = (const float*)d_in[10];
    const float* Wl1 = (const float*)d_in[11];
    const float* bl1 = (const float*)d_in[12];
    const float* Wl2 = (const float*)d_in[13];
    const float* bl2 = (const float*)d_in[14];
    const float* Wl3 = (const float*)d_in[15];
    const float* bl3 = (const float*)d_in[16];
    float* out = (float*)d_out;

    const int N = in_sizes[0] / 9;
    const int E = in_sizes[1] / 2;

    char* ws = (char*)d_ws;
    size_t off = 0;
    auto alloc = [&](size_t bytes) -> void* {
        void* p = ws + off;
        off += (bytes + 255) & ~(size_t)255;
        return p;
    };
    __half* h16    = (__half*)alloc((size_t)N * 128 * sizeof(__half));  // 25.6 MB
    __half* agg16  = (__half*)alloc((size_t)N * 128 * sizeof(__half));  // 25.6 MB
    __half* a32    = (__half*)alloc((size_t)N * 32 * sizeof(__half));   // 6.4 MB
    __half* x16    = (__half*)alloc((size_t)N * 16 * sizeof(__half));   // 3.2 MB
    int* rs     = (int*)alloc((size_t)(N + 1) * sizeof(int));
    int* csr    = (int*)alloc((size_t)E * sizeof(int));                  // 6.4 MB
    int* staged = (int*)alloc((size_t)E * sizeof(int));                  // 6.4 MB
    _Float16* wpk1  = (_Float16*)alloc(32 * 128 * sizeof(_Float16));
    _Float16* wpk2l = (_Float16*)alloc(128 * 128 * sizeof(_Float16));
    _Float16* wpk2r = (_Float16*)alloc(128 * 128 * sizeof(_Float16));
    _Float16* wpk3l = (_Float16*)alloc(128 * 128 * sizeof(_Float16));
    _Float16* wpk3r = (_Float16*)alloc(128 * 128 * sizeof(_Float16));
    _Float16* wpkl1 = (_Float16*)alloc(128 * 128 * sizeof(_Float16));
    _Float16* wpkl2 = (_Float16*)alloc(128 * 64 * sizeof(_Float16));
    (void)ws_size; (void)n_in; (void)out_size;

    // bucket params (N=100K, E=1.6M -> shift=7, NB=782, NBLK=782)
    int shift = 7;
    while ((((size_t)N + ((size_t)1 << shift) - 1) >> shift) > MAXNB) ++shift;
    const int NB = (N + (1 << shift) - 1) >> shift;
    const int NBLK = (E + CH - 1) / CH;               // <= 1024 (scan capacity)
    int* bh    = (int*)alloc((size_t)NB * NBLK * sizeof(int));          // 2.4 MB
    int* btot  = (int*)alloc((size_t)NB * sizeof(int));
    int* bbase = (int*)alloc((size_t)(NB + 1) * sizeof(int));
    int* bsum  = (int*)alloc(64 * sizeof(int));

    // Weight packing + x fp16 mirror (independent of CSR build)
    WPD6 wp;
    wp.d[0] = {W2l, wpk2l, 128, 128};
    wp.d[1] = {W2r, wpk2r, 128, 128};
    wp.d[2] = {W3l, wpk3l, 128, 128};
    wp.d[3] = {W3r, wpk3r, 128, 128};
    wp.d[4] = {Wl1, wpkl1, 128, 128};
    wp.d[5] = {Wl2, wpkl2, 128, 64};
    wpack6_k<<<dim3(8, 6), 256, 0, stream>>>(wp);
    wpack1_k<<<2, 256, 0, stream>>>(W1l, W1r, wpk1);
    xcast_k<<<(N + 255) / 256, 256, 0, stream>>>(x, x16, N);

    // CSR build (two-level bucket, no global-atomic scatter)
    bhist_k<<<NBLK, 256, 0, stream>>>(ei, bh, E, shift, NB, NBLK);
    scan_col_k<<<NB, 256, 0, stream>>>(bh, btot, NBLK, NB);
    scan_block_k<<<1, 256, 0, stream>>>(btot, bbase, bsum, NB);
    bscatter_k<<<NBLK, 256, 0, stream>>>(ei, bh, bbase, staged, E, shift, NB, NBLK);
    csrfill_k<<<NB, 256, 0, stream>>>(staged, bbase, rs, csr, N, E, shift, NB);

    const int gemm_grid = (N + 63) / 64;
    const int agg_grid = (N + 15) / 16;

    // SAGE layer 1 (9 -> 128): pack [mean9|x9|0] fp16, then K=32 MFMA GEMM
    agg9pack_k<<<(N + 255) / 256, 256, 0, stream>>>(x16, rs, csr, a32, N);
    mfma_lin_k<2, 1, 32><<<gemm_grid, 256, 0, stream>>>(
        a32, nullptr, wpk1, nullptr, b1, h16, N);

    // SAGE layer 2 (128 -> 128): gather h1 -> agg16; h2 = relu(agg@W2l + h1@W2r + b2)
    agg128h4_k<<<agg_grid, 256, 0, stream>>>(h16, rs, csr, agg16, N);
    mfma_lin_k<2, 2, 128><<<gemm_grid, 256, 0, stream>>>(
        agg16, h16, wpk2l, wpk2r, b2, h16, N);

    // SAGE layer 3 (128 -> 128)
    agg128h4_k<<<agg_grid, 256, 0, stream>>>(h16, rs, csr, agg16, N);
    mfma_lin_k<2, 2, 128><<<gemm_grid, 256, 0, stream>>>(
        agg16, h16, wpk3l, wpk3r, b3, h16, N);

    // MLP: 128 -> 128 (relu) GEMM, then fused {128->64 relu GEMM + 64->3 +
    // log_softmax} tail
    mfma_lin_k<2, 1, 128><<<gemm_grid, 256, 0, stream>>>(
        h16, nullptr, wpkl1, nullptr, bl1, h16, N);
    mfma_lin_final_k<<<gemm_grid, 256, 0, stream>>>(
        h16, wpkl2, bl2, Wl3, bl3, out, N);
}